// Round 7
// baseline (441.978 us; speedup 1.0000x reference)
//
#include <hip/hip_runtime.h>

// Problem constants (fixed shapes from the reference file)
#define BB 32
#define SS 1024
#define HH 384
#define MAXLEN 8192
#define H4 (HH / 4)                 // 96 float4 per row
#define OUT0 (BB * MAXLEN * HH)     // 100663296 floats: the expanded output
#define MEL_OFF OUT0                // 32 floats: mel_len (as f32)
#define MASK_OFF (OUT0 + BB)        // 262144 floats: mel_mask

// Native 16B vector type: __builtin_nontemporal_store rejects HIP's float4
// (struct-wrapped), but accepts clang ext_vector_type.
typedef float vfloat4 __attribute__((ext_vector_type(4)));

// ---------------------------------------------------------------------------
// Single fused kernel, 16384 blocks x 256 threads, 16 frames per block
// exactly (256 thr x 6 float4 = 1536 = 16*96).
//
// Each block redundantly computes its batch's duration cumsum itself:
//   int4 load (4 dur/thread) -> thread-local inclusive -> wave shuffle scan
//   -> 4-wave LDS combine -> cum[1024] in LDS. ~25 extra VALU instr/thread,
//   hidden under the block's 1.5 MB HBM traffic (expand ran at ~5% VALUBusy).
// This removes the k_prep launch, the prep->expand stream serialization, and
// the idxbuf 2 MB global round-trip (R6's last measurable costs).
//
// The 16 threads matching this block's frames binary-search cum; mask floats
// and (for 32 blocks) mel_len are written here too. bool inputs arrive
// widened to int32 (R1's absmax==1.0 proved the byte-wise read wrong).
//
// XCD swizzle: physical block L -> work W = (L%8)*(NB/8)+L/8, so each XCD
// owns a contiguous 1/8 of the output; nontemporal stores keep L2 for x.
// ---------------------------------------------------------------------------
#define FPB 16
#define ITEMS 6
#define NB_EXP (BB * MAXLEN / FPB)   // 16384 blocks
__global__ __launch_bounds__(256) void k_fused(
    const vfloat4* __restrict__ x4,
    const int* __restrict__ dur,
    const int* __restrict__ mel_mask_in,
    float* __restrict__ out)
{
    __shared__ int cum[SS];
    __shared__ int wsum[4];
    __shared__ int sidx[FPB];

    const int L = blockIdx.x;
    const int W = (L & 7) * (NB_EXP / 8) + (L >> 3);
    const int f0 = W * FPB;                 // global frame base = b*8192 + t0
    const int b  = f0 >> 13;                // 8192 % 16 == 0: no batch straddle
    const int t0 = f0 & (MAXLEN - 1);
    const int tid = threadIdx.x;
    const int lane = tid & 63;
    const int wid = tid >> 6;               // 4 waves

    // ---- duration scan: 4 durations per thread (int4, coalesced) ----
    const int4 d4 = ((const int4*)dur)[b * (SS / 4) + tid];
    const int l0 = d4.x;
    const int l1 = l0 + d4.y;
    const int l2 = l1 + d4.z;
    const int l3 = l2 + d4.w;               // thread-local sum
    int v = l3;
#pragma unroll
    for (int o = 1; o < 64; o <<= 1) {      // wave inclusive scan of totals
        int u = __shfl_up(v, o, 64);
        if (lane >= o) v += u;
    }
    if (lane == 63) wsum[wid] = v;
    __syncthreads();
    int woff = 0;
#pragma unroll
    for (int w = 0; w < 3; ++w) woff += (wid > w) ? wsum[w] : 0;
    const int excl = woff + v - l3;         // exclusive prefix for this thread
    cum[4 * tid + 0] = excl + l0;
    cum[4 * tid + 1] = excl + l1;
    cum[4 * tid + 2] = excl + l2;
    cum[4 * tid + 3] = excl + l3;
    __syncthreads();

    const int mel_len = cum[SS - 1];
    if (t0 == 0 && tid == 0) out[MEL_OFF + b] = (float)mel_len;

    // ---- 16 threads: searchsorted + mask for this block's frames ----
    if (tid < FPB) {
        const int t = t0 + tid;
        int lo = 0, hi = SS;
        while (lo < hi) {
            int mid = (lo + hi) >> 1;
            if (cum[mid] <= t) lo = mid + 1; else hi = mid;
        }
        int idx = (lo < SS) ? lo : (SS - 1);
        sidx[tid] = (t < mel_len) ? idx : -1;
        out[MASK_OFF + b * MAXLEN + t] = mel_mask_in[b * MAXLEN + t] ? 1.0f : 0.0f;
    }
    __syncthreads();

    // ---- expansion: 16 frames x 96 float4, coalesced, nontemporal ----
    const size_t xb = (size_t)b * SS * H4;
    const size_t ob = (size_t)f0 * H4;
    vfloat4* __restrict__ out4 = (vfloat4*)out;
#pragma unroll
    for (int k = 0; k < ITEMS; ++k) {
        const int j = tid + k * 256;        // 0..1535
        const int fl = j / H4;              // local frame 0..15
        const int c  = j - fl * H4;
        const int id = sidx[fl];
        vfloat4 val = (vfloat4)(0.f);
        if (id >= 0) val = x4[xb + (size_t)id * H4 + c];
        __builtin_nontemporal_store(val, &out4[ob + j]);
    }
}

extern "C" void kernel_launch(void* const* d_in, const int* in_sizes, int n_in,
                              void* d_out, int out_size, void* d_ws, size_t ws_size,
                              hipStream_t stream) {
    // setup_inputs order: x, src_mask, mel_mask, duration_target, pitch_target, max_len
    const float* x = (const float*)d_in[0];
    const int* mel_mask_in = (const int*)d_in[2];
    const int* dur = (const int*)d_in[3];
    float* out = (float*)d_out;

    k_fused<<<NB_EXP, 256, 0, stream>>>((const vfloat4*)x, dur, mel_mask_in, out);
}